// Round 1
// baseline (619.356 us; speedup 1.0000x reference)
//
#include <hip/hip_runtime.h>

#define H 1024
#define BATCH 8192
#define NSTEPS 50

// ---------------------------------------------------------------------------
// Setup: A = I + h*W (also copied into P), c = h*b (also copied into v0)
// ---------------------------------------------------------------------------
__global__ void build_A_k(float* __restrict__ A, float* __restrict__ P,
                          const float* __restrict__ W,
                          const float* __restrict__ t0, const float* __restrict__ t1)
{
    const float h = (t1[0] - t0[0]) / (float)NSTEPS;
    const int idx = blockIdx.x * 256 + threadIdx.x;
    const int r = idx >> 10;          // / 1024
    const int c = idx & 1023;         // % 1024
    const float v = h * W[idx] + (r == c ? 1.0f : 0.0f);
    A[idx] = v;
    P[idx] = v;
}

__global__ void build_c_k(float* __restrict__ cvec, float* __restrict__ v0,
                          const float* __restrict__ b,
                          const float* __restrict__ t0, const float* __restrict__ t1)
{
    const float h = (t1[0] - t0[0]) / (float)NSTEPS;
    const int i = blockIdx.x * 256 + threadIdx.x;
    const float v = h * b[i];
    cvec[i] = v;
    v0[i] = v;
}

// ---------------------------------------------------------------------------
// matvec: y = add + Mat * x    (Mat is H x H row-major; y,x,add length H)
// 256 threads = 4 waves per block, one row per wave; grid = H/4 blocks.
// ---------------------------------------------------------------------------
__global__ void matvec_add_k(float* __restrict__ y, const float* __restrict__ Mat,
                             const float* __restrict__ x, const float* __restrict__ add)
{
    const int wave = threadIdx.x >> 6;
    const int lane = threadIdx.x & 63;
    const int row = blockIdx.x * 4 + wave;
    const float* mr = Mat + (size_t)row * H;
    float s = 0.0f;
    #pragma unroll
    for (int j = 0; j < H / 64; ++j)
        s = fmaf(mr[lane + j * 64], x[lane + j * 64], s);
    #pragma unroll
    for (int off = 32; off; off >>= 1)
        s += __shfl_down(s, off, 64);
    if (lane == 0) y[row] = add[row] + s;
}

// ---------------------------------------------------------------------------
// SGEMM: C = A * B (+ bias per-row), row-major, exact-multiple dims.
//   A: M x K, B: K x N, C: M x N, bias: length M or nullptr
// Block tile BM x BN, K-step BK, per-thread microtile TM x TN. 256 threads.
// ---------------------------------------------------------------------------
template<int BM, int BN, int BK, int TM, int TN>
__launch_bounds__(256)
__global__ void sgemm_k(const float* __restrict__ A, const float* __restrict__ Bm,
                        float* __restrict__ C, const float* __restrict__ bias,
                        int M, int N, int K)
{
    constexpr int TX = BN / TN;
    constexpr int TY = BM / TM;
    static_assert(TX * TY == 256, "256 threads");
    constexpr int A_IT = (BM * BK / 4) / 256;   // float4 loads per thread (A tile)
    constexpr int B_IT = (BK * BN / 4) / 256;   // float4 loads per thread (B tile)
    static_assert(A_IT >= 1 && B_IT >= 1, "tile sizes");

    __shared__ float As[BK][BM];   // transposed A tile
    __shared__ float Bs[BK][BN];

    const int tid = threadIdx.x;
    const int tx = tid % TX;
    const int ty = tid / TX;
    const int row0 = blockIdx.y * BM;
    const int col0 = blockIdx.x * BN;

    float acc[TM][TN];
    #pragma unroll
    for (int m = 0; m < TM; ++m)
        #pragma unroll
        for (int n = 0; n < TN; ++n) acc[m][n] = 0.0f;

    for (int k0 = 0; k0 < K; k0 += BK) {
        // stage A tile (BM x BK) -> As[k][m] (transposed)
        #pragma unroll
        for (int it = 0; it < A_IT; ++it) {
            const int f = tid + it * 256;
            const int r = f / (BK / 4);
            const int kq = (f % (BK / 4)) * 4;
            const float4 v = *(const float4*)&A[(size_t)(row0 + r) * K + k0 + kq];
            As[kq + 0][r] = v.x;
            As[kq + 1][r] = v.y;
            As[kq + 2][r] = v.z;
            As[kq + 3][r] = v.w;
        }
        // stage B tile (BK x BN) -> Bs[k][n]
        #pragma unroll
        for (int it = 0; it < B_IT; ++it) {
            const int f = tid + it * 256;
            const int r = f / (BN / 4);
            const int j = (f % (BN / 4)) * 4;
            *(float4*)&Bs[r][j] = *(const float4*)&Bm[(size_t)(k0 + r) * N + col0 + j];
        }
        __syncthreads();

        #pragma unroll
        for (int kk = 0; kk < BK; ++kk) {
            float a[TM], bfr[TN];
            #pragma unroll
            for (int m = 0; m < TM; m += 4)
                *(float4*)&a[m] = *(const float4*)&As[kk][ty * TM + m];
            #pragma unroll
            for (int n = 0; n < TN; n += 4)
                *(float4*)&bfr[n] = *(const float4*)&Bs[kk][tx * TN + n];
            #pragma unroll
            for (int m = 0; m < TM; ++m)
                #pragma unroll
                for (int n = 0; n < TN; ++n)
                    acc[m][n] = fmaf(a[m], bfr[n], acc[m][n]);
        }
        __syncthreads();
    }

    #pragma unroll
    for (int m = 0; m < TM; ++m) {
        const int r = row0 + ty * TM + m;
        const float bv = bias ? bias[r] : 0.0f;
        #pragma unroll
        for (int n = 0; n < TN; n += 4) {
            float4 v;
            v.x = acc[m][n + 0] + bv;
            v.y = acc[m][n + 1] + bv;
            v.z = acc[m][n + 2] + bv;
            v.w = acc[m][n + 3] + bv;
            *(float4*)&C[(size_t)r * N + col0 + tx * TN + n] = v;
        }
    }
}

// ---------------------------------------------------------------------------
// host-side launcher
// ---------------------------------------------------------------------------
extern "C" void kernel_launch(void* const* d_in, const int* in_sizes, int n_in,
                              void* d_out, int out_size, void* d_ws, size_t ws_size,
                              hipStream_t stream)
{
    const float* x0 = (const float*)d_in[0];
    const float* t0 = (const float*)d_in[1];
    const float* t1 = (const float*)d_in[2];
    const float* W  = (const float*)d_in[3];
    const float* bb = (const float*)d_in[4];
    float* out = (float*)d_out;

    // workspace layout (floats): A | P | Q | c | v0 | v1   (~12.6 MB)
    float* A  = (float*)d_ws;
    float* P  = A + (size_t)H * H;
    float* Q  = P + (size_t)H * H;
    float* cv = Q + (size_t)H * H;
    float* v0 = cv + H;
    float* v1 = v0 + H;

    build_A_k<<<H * H / 256, 256, 0, stream>>>(A, P, W, t0, t1);
    build_c_k<<<H / 256, 256, 0, stream>>>(cv, v0, bb, t0, t1);

    float* vin = v0;
    float* vout = v1;

    // addition chain for 50: 1 ->(sq) 2 ->(mul) 3 ->(sq) 6 ->(sq) 12 ->(sq) 24
    //                          ->(mul) 25 ->(sq) 50
    // sq : v_{2n} = v_n + P v_n ;  P <- P*P
    // mul: v_{n+1} = c + A v_n  ;  P <- A*P
    const dim3 gs(H / 64, H / 64);
    #define SQ_STEP() do { \
        matvec_add_k<<<H / 4, 256, 0, stream>>>(vout, P, vin, vin); \
        sgemm_k<64, 64, 16, 4, 4><<<gs, 256, 0, stream>>>(P, P, Q, nullptr, H, H, H); \
        { float* t = P; P = Q; Q = t; t = vin; vin = vout; vout = t; } \
    } while (0)
    #define MUL_STEP() do { \
        matvec_add_k<<<H / 4, 256, 0, stream>>>(vout, A, vin, cv); \
        sgemm_k<64, 64, 16, 4, 4><<<gs, 256, 0, stream>>>(A, P, Q, nullptr, H, H, H); \
        { float* t = P; P = Q; Q = t; t = vin; vin = vout; vout = t; } \
    } while (0)

    SQ_STEP();   // n = 2
    MUL_STEP();  // n = 3
    SQ_STEP();   // n = 6
    SQ_STEP();   // n = 12
    SQ_STEP();   // n = 24
    MUL_STEP();  // n = 25
    SQ_STEP();   // n = 50

    #undef SQ_STEP
    #undef MUL_STEP

    // out = A^50 * x0 + v50 (broadcast over batch)
    sgemm_k<128, 128, 16, 8, 8>
        <<<dim3(BATCH / 128, H / 128), 256, 0, stream>>>(P, x0, out, vin, H, BATCH, H);
}

// Round 2
// 349.512 us; speedup vs baseline: 1.7721x; 1.7721x over previous
//
#include <hip/hip_runtime.h>

#define H 1024
#define BATCH 8192
#define NSTEPS 50
#define SPLITK 4

typedef __attribute__((ext_vector_type(8))) short bf16x8;
typedef __attribute__((ext_vector_type(4))) float f32x4;

// ---------------------------------------------------------------------------
// fp32 -> (hi, lo) bf16 split: a ~= hi + lo, |a - hi - lo| <= ~2^-17 |a|
// ---------------------------------------------------------------------------
__device__ __forceinline__ void split2(float a, short& h, short& l)
{
    unsigned u = __float_as_uint(a);
    unsigned hu = u & 0xFFFF0000u;
    float r = a - __uint_as_float(hu);     // exact
    unsigned ru = __float_as_uint(r);
    h = (short)(u >> 16);                  // truncated bf16
    l = (short)((ru + 0x8000u) >> 16);     // rounded bf16 of residual
}

// ---------------------------------------------------------------------------
// Setup: A = I + h*W (also copied into P), c = h*b (also copied into v0)
// ---------------------------------------------------------------------------
__global__ void build_A_k(float* __restrict__ A, float* __restrict__ P,
                          const float* __restrict__ W,
                          const float* __restrict__ t0, const float* __restrict__ t1)
{
    const float h = (t1[0] - t0[0]) / (float)NSTEPS;
    const int idx = blockIdx.x * 256 + threadIdx.x;
    const int r = idx >> 10;
    const int c = idx & 1023;
    const float v = h * W[idx] + (r == c ? 1.0f : 0.0f);
    A[idx] = v;
    P[idx] = v;
}

__global__ void build_c_k(float* __restrict__ cvec, float* __restrict__ v0,
                          const float* __restrict__ b,
                          const float* __restrict__ t0, const float* __restrict__ t1)
{
    const float h = (t1[0] - t0[0]) / (float)NSTEPS;
    const int i = blockIdx.x * 256 + threadIdx.x;
    const float v = h * b[i];
    cvec[i] = v;
    v0[i] = v;
}

// ---------------------------------------------------------------------------
// matvec: y = add + Mat * x
// ---------------------------------------------------------------------------
__global__ void matvec_add_k(float* __restrict__ y, const float* __restrict__ Mat,
                             const float* __restrict__ x, const float* __restrict__ add)
{
    const int wave = threadIdx.x >> 6;
    const int lane = threadIdx.x & 63;
    const int row = blockIdx.x * 4 + wave;
    const float* mr = Mat + (size_t)row * H;
    float s = 0.0f;
    #pragma unroll
    for (int j = 0; j < H / 64; ++j)
        s = fmaf(mr[lane + j * 64], x[lane + j * 64], s);
    #pragma unroll
    for (int off = 32; off; off >>= 1)
        s += __shfl_down(s, off, 64);
    if (lane == 0) y[row] = add[row] + s;
}

// ---------------------------------------------------------------------------
// fp32 SGEMM with split-K: block z computes C_partial[z] over k in
// [z*kLen, (z+1)*kLen). Partials written to C + z*M*N.
// ---------------------------------------------------------------------------
template<int BM, int BN, int BK, int TM, int TN>
__launch_bounds__(256)
__global__ void sgemm_k(const float* __restrict__ A, const float* __restrict__ Bm,
                        float* __restrict__ C, int M, int N, int K, int kLen)
{
    constexpr int TX = BN / TN;
    constexpr int TY = BM / TM;
    static_assert(TX * TY == 256, "256 threads");
    constexpr int A_IT = (BM * BK / 4) / 256;
    constexpr int B_IT = (BK * BN / 4) / 256;

    __shared__ float As[BK][BM + 4];   // +4 pad: aligned float4 rows, no bank conflict
    __shared__ float Bs[BK][BN + 4];

    const int tid = threadIdx.x;
    const int tx = tid % TX;
    const int ty = tid / TX;
    const int row0 = blockIdx.y * BM;
    const int col0 = blockIdx.x * BN;
    const int kbeg = blockIdx.z * kLen;

    float acc[TM][TN];
    #pragma unroll
    for (int m = 0; m < TM; ++m)
        #pragma unroll
        for (int n = 0; n < TN; ++n) acc[m][n] = 0.0f;

    for (int k0 = kbeg; k0 < kbeg + kLen; k0 += BK) {
        #pragma unroll
        for (int it = 0; it < A_IT; ++it) {
            const int f = tid + it * 256;
            const int r = f / (BK / 4);
            const int kq = (f % (BK / 4)) * 4;
            const float4 v = *(const float4*)&A[(size_t)(row0 + r) * K + k0 + kq];
            As[kq + 0][r] = v.x;
            As[kq + 1][r] = v.y;
            As[kq + 2][r] = v.z;
            As[kq + 3][r] = v.w;
        }
        #pragma unroll
        for (int it = 0; it < B_IT; ++it) {
            const int f = tid + it * 256;
            const int r = f / (BN / 4);
            const int j = (f % (BN / 4)) * 4;
            *(float4*)&Bs[r][j] = *(const float4*)&Bm[(size_t)(k0 + r) * N + col0 + j];
        }
        __syncthreads();

        #pragma unroll
        for (int kk = 0; kk < BK; ++kk) {
            float a[TM], bfr[TN];
            #pragma unroll
            for (int m = 0; m < TM; m += 4)
                *(float4*)&a[m] = *(const float4*)&As[kk][ty * TM + m];
            #pragma unroll
            for (int n = 0; n < TN; n += 4)
                *(float4*)&bfr[n] = *(const float4*)&Bs[kk][tx * TN + n];
            #pragma unroll
            for (int m = 0; m < TM; ++m)
                #pragma unroll
                for (int n = 0; n < TN; ++n)
                    acc[m][n] = fmaf(a[m], bfr[n], acc[m][n]);
        }
        __syncthreads();
    }

    float* Cz = C + (size_t)blockIdx.z * M * N;
    #pragma unroll
    for (int m = 0; m < TM; ++m) {
        const int r = row0 + ty * TM + m;
        #pragma unroll
        for (int n = 0; n < TN; n += 4)
            *(float4*)&Cz[(size_t)r * N + col0 + tx * TN + n] = *(float4*)&acc[m][n];
    }
}

// ---------------------------------------------------------------------------
// reduce the SPLITK partials: dst[i] = sum_z part[z][i]   (float4 granular)
// ---------------------------------------------------------------------------
__global__ void reduce4_k(float* __restrict__ dst, const float* __restrict__ part)
{
    const int i = blockIdx.x * 256 + threadIdx.x;      // float4 index
    float4 s = ((const float4*)part)[i];
    #pragma unroll
    for (int z = 1; z < SPLITK; ++z) {
        const float4 p = ((const float4*)(part + (size_t)z * H * H))[i];
        s.x += p.x; s.y += p.y; s.z += p.z; s.w += p.w;
    }
    ((float4*)dst)[i] = s;
}

// ---------------------------------------------------------------------------
// split a full fp32 matrix into bf16 hi/lo planes (float4 granular)
// ---------------------------------------------------------------------------
__global__ void split_mat_k(const float* __restrict__ M, short* __restrict__ hi,
                            short* __restrict__ lo)
{
    const int i = blockIdx.x * 256 + threadIdx.x;      // float4 index
    const float4 v = ((const float4*)M)[i];
    short4 hv, lv;
    split2(v.x, hv.x, lv.x);
    split2(v.y, hv.y, lv.y);
    split2(v.z, hv.z, lv.z);
    split2(v.w, hv.w, lv.w);
    ((short4*)hi)[i] = hv;
    ((short4*)lo)[i] = lv;
}

// ---------------------------------------------------------------------------
// Big GEMM on matrix cores: C = P * X + bias, P pre-split (bf16 hi/lo),
// X fp32 split on the fly. C: 1024 x 8192. Tile 128x128, BK=32, 4 waves.
// Per wave: 64x64 out = 4x4 fragments of 16x16; 3 MFMA per fragment pair.
// ---------------------------------------------------------------------------
#define PADK 40   // 32 + 8 shorts: 80B rows, 16B aligned, 2-way-max reads

__launch_bounds__(256)
__global__ void mfma_gemm_k(const short* __restrict__ Ahi_g, const short* __restrict__ Alo_g,
                            const float* __restrict__ X, float* __restrict__ C,
                            const float* __restrict__ bias)
{
    __shared__ short Ahi[128][PADK], Alo[128][PADK];
    __shared__ short Bhi[128][PADK], Blo[128][PADK];

    const int tid = threadIdx.x;
    const int wave = tid >> 6;
    const int lane = tid & 63;
    const int wr = (wave >> 1) * 64;    // wave m offset within tile
    const int wc = (wave & 1) * 64;     // wave n offset within tile
    const int m0 = blockIdx.y * 128;
    const int n0 = blockIdx.x * 128;
    const int lg = lane >> 4;           // k-group (0..3)
    const int lm = lane & 15;

    f32x4 acc[4][4] = {};

    for (int k0 = 0; k0 < H; k0 += 32) {
        // stage A (bf16 pre-split, row-major [128][32])
        #pragma unroll
        for (int a2 = 0; a2 < 2; ++a2) {
            const int id = tid + a2 * 256;          // 0..511
            const int row = id >> 2;
            const int ko = id & 3;
            const size_t g = (size_t)(m0 + row) * H + k0 + ko * 8;
            *(bf16x8*)&Ahi[row][ko * 8] = *(const bf16x8*)&Ahi_g[g];
            *(bf16x8*)&Alo[row][ko * 8] = *(const bf16x8*)&Alo_g[g];
        }
        // stage B transposed: X[k][n] fp32 -> Bhi/Blo[n][k] bf16
        #pragma unroll
        for (int a2 = 0; a2 < 2; ++a2) {
            const int id = tid + a2 * 256;          // 0..511
            const int n = id & 127;
            const int ko = id >> 7;                 // 0..3
            const float* src = &X[(size_t)(k0 + ko * 8) * BATCH + n0 + n];
            bf16x8 bh, bl;
            #pragma unroll
            for (int i = 0; i < 8; ++i) {
                short hh, ll;
                split2(src[(size_t)i * BATCH], hh, ll);
                bh[i] = hh;
                bl[i] = ll;
            }
            *(bf16x8*)&Bhi[n][ko * 8] = bh;
            *(bf16x8*)&Blo[n][ko * 8] = bl;
        }
        __syncthreads();

        bf16x8 ah[4], al[4], bh[4], bl[4];
        #pragma unroll
        for (int i = 0; i < 4; ++i) {
            const int m = wr + i * 16 + lm;
            ah[i] = *(const bf16x8*)&Ahi[m][lg * 8];
            al[i] = *(const bf16x8*)&Alo[m][lg * 8];
            const int n = wc + i * 16 + lm;
            bh[i] = *(const bf16x8*)&Bhi[n][lg * 8];
            bl[i] = *(const bf16x8*)&Blo[n][lg * 8];
        }
        #pragma unroll
        for (int i = 0; i < 4; ++i)
            #pragma unroll
            for (int j = 0; j < 4; ++j) {
                acc[i][j] = __builtin_amdgcn_mfma_f32_16x16x32_bf16(ah[i], bh[j], acc[i][j], 0, 0, 0);
                acc[i][j] = __builtin_amdgcn_mfma_f32_16x16x32_bf16(ah[i], bl[j], acc[i][j], 0, 0, 0);
                acc[i][j] = __builtin_amdgcn_mfma_f32_16x16x32_bf16(al[i], bh[j], acc[i][j], 0, 0, 0);
            }
        __syncthreads();
    }

    // epilogue: C row = m0+wr+i*16+lg*4+r, col = n0+wc+j*16+lm  (m89 layout)
    #pragma unroll
    for (int i = 0; i < 4; ++i) {
        const int rowb = m0 + wr + i * 16 + lg * 4;
        #pragma unroll
        for (int r = 0; r < 4; ++r) {
            const float bv = bias[rowb + r];
            float* dst = &C[(size_t)(rowb + r) * BATCH + n0 + wc + lm];
            #pragma unroll
            for (int j = 0; j < 4; ++j)
                dst[j * 16] = acc[i][j][r] + bv;
        }
    }
}

// ---------------------------------------------------------------------------
// host-side launcher
// ---------------------------------------------------------------------------
extern "C" void kernel_launch(void* const* d_in, const int* in_sizes, int n_in,
                              void* d_out, int out_size, void* d_ws, size_t ws_size,
                              hipStream_t stream)
{
    const float* x0 = (const float*)d_in[0];
    const float* t0 = (const float*)d_in[1];
    const float* t1 = (const float*)d_in[2];
    const float* W  = (const float*)d_in[3];
    const float* bb = (const float*)d_in[4];
    float* out = (float*)d_out;

    // workspace layout (floats): A | P | Q | c | v0 | v1   (~12.6 MB)
    float* A  = (float*)d_ws;
    float* P  = A + (size_t)H * H;
    float* Q  = P + (size_t)H * H;
    float* cv = Q + (size_t)H * H;
    float* v0 = cv + H;
    float* v1 = v0 + H;

    build_A_k<<<H * H / 256, 256, 0, stream>>>(A, P, W, t0, t1);
    build_c_k<<<H / 256, 256, 0, stream>>>(cv, v0, bb, t0, t1);

    float* vin = v0;
    float* vout = v1;

    // addition chain for 50: 1 -> 2 -> 3 -> 6 -> 12 -> 24 -> 25 -> 50
    // sq : v_{2n} = v_n + P v_n ;  P <- P*P
    // mul: v_{n+1} = c + A v_n  ;  P <- A*P
    // split-K=4 fp32 GEMM, partials staged in d_out (overwritten at the end)
    const dim3 gs(H / 64, H / 64, SPLITK);
    #define SQ_STEP() do { \
        matvec_add_k<<<H / 4, 256, 0, stream>>>(vout, P, vin, vin); \
        sgemm_k<64, 64, 16, 4, 4><<<gs, 256, 0, stream>>>(P, P, out, H, H, H, H / SPLITK); \
        reduce4_k<<<H * H / 4 / 256, 256, 0, stream>>>(Q, out); \
        { float* t = P; P = Q; Q = t; t = vin; vin = vout; vout = t; } \
    } while (0)
    #define MUL_STEP() do { \
        matvec_add_k<<<H / 4, 256, 0, stream>>>(vout, A, vin, cv); \
        sgemm_k<64, 64, 16, 4, 4><<<gs, 256, 0, stream>>>(A, P, out, H, H, H, H / SPLITK); \
        reduce4_k<<<H * H / 4 / 256, 256, 0, stream>>>(Q, out); \
        { float* t = P; P = Q; Q = t; t = vin; vin = vout; vout = t; } \
    } while (0)

    SQ_STEP();   // n = 2
    MUL_STEP();  // n = 3
    SQ_STEP();   // n = 6
    SQ_STEP();   // n = 12
    SQ_STEP();   // n = 24
    MUL_STEP();  // n = 25
    SQ_STEP();   // n = 50

    #undef SQ_STEP
    #undef MUL_STEP

    // A (=I+hW) is dead now: reuse its 4 MB as the bf16 hi/lo planes of A^50
    short* Phi = (short*)A;
    short* Plo = Phi + (size_t)H * H;
    split_mat_k<<<H * H / 4 / 256, 256, 0, stream>>>(P, Phi, Plo);

    // out = A^50 * x0 + v50 (matrix cores, 2-way bf16 split, 3 products)
    mfma_gemm_k<<<dim3(BATCH / 128, H / 128), 256, 0, stream>>>(Phi, Plo, x0, out, vin);
}

// Round 3
// 280.674 us; speedup vs baseline: 2.2067x; 1.2453x over previous
//
#include <hip/hip_runtime.h>

#define H 1024
#define HH (H * H)
#define BATCH 8192
#define NSTEPS 50

typedef __attribute__((ext_vector_type(8))) short bf16x8;
typedef __attribute__((ext_vector_type(4))) float f32x4;

// ---------------------------------------------------------------------------
// helpers
// ---------------------------------------------------------------------------
__device__ __forceinline__ void split2(float a, unsigned short& h, unsigned short& l)
{
    unsigned u = __float_as_uint(a);
    float r = a - __uint_as_float(u & 0xFFFF0000u);   // exact residual
    h = (unsigned short)(u >> 16);                    // truncated bf16
    l = (unsigned short)((__float_as_uint(r) + 0x8000u) >> 16); // rounded residual
}
__device__ __forceinline__ float bf2f(unsigned short s)
{
    return __uint_as_float(((unsigned)s) << 16);
}
__device__ __forceinline__ void gload16(const void* g, void* l)
{
    __builtin_amdgcn_global_load_lds(
        (const __attribute__((address_space(1))) void*)g,
        (__attribute__((address_space(3))) void*)l, 16, 0, 0);
}

// ---------------------------------------------------------------------------
// build A = I + h*W as bf16 hi/lo planes; c = h*b (fp32, also v0)
// ---------------------------------------------------------------------------
__global__ void build_k(unsigned short* __restrict__ Ahi, unsigned short* __restrict__ Alo,
                        const float* __restrict__ W,
                        const float* __restrict__ t0, const float* __restrict__ t1)
{
    const float h = (t1[0] - t0[0]) / (float)NSTEPS;
    const int i4 = blockIdx.x * 256 + threadIdx.x;   // float4 index
    const int idx = i4 * 4;
    const int r = idx >> 10;
    const int cb = idx & 1023;
    const float4 w = ((const float4*)W)[i4];
    float a[4] = {h * w.x, h * w.y, h * w.z, h * w.w};
    #pragma unroll
    for (int j = 0; j < 4; ++j)
        if (cb + j == r) a[j] += 1.0f;
    ushort4 hv, lv;
    split2(a[0], hv.x, lv.x);
    split2(a[1], hv.y, lv.y);
    split2(a[2], hv.z, lv.z);
    split2(a[3], hv.w, lv.w);
    ((ushort4*)Ahi)[i4] = hv;
    ((ushort4*)Alo)[i4] = lv;
}

__global__ void build_c_k(float* __restrict__ cvec, float* __restrict__ v0,
                          const float* __restrict__ b,
                          const float* __restrict__ t0, const float* __restrict__ t1)
{
    const float h = (t1[0] - t0[0]) / (float)NSTEPS;
    const int i = blockIdx.x * 256 + threadIdx.x;
    const float v = h * b[i];
    cvec[i] = v;
    v0[i] = v;
}

// ---------------------------------------------------------------------------
// transpose a pair of bf16 planes (1024x1024): D = S^T
// ---------------------------------------------------------------------------
__global__ void transpose_pair_k(const unsigned short* __restrict__ Shi,
                                 const unsigned short* __restrict__ Slo,
                                 unsigned short* __restrict__ Dhi,
                                 unsigned short* __restrict__ Dlo)
{
    __shared__ unsigned short th[64][68], tl[64][68];
    const int t = threadIdx.x;
    const int cb = blockIdx.x * 64;  // src col base
    const int rb = blockIdx.y * 64;  // src row base
    #pragma unroll
    for (int p = 0; p < 4; ++p) {
        const int row = p * 16 + (t >> 4);
        const int c4 = (t & 15) * 4;
        *(ushort4*)&th[row][c4] = *(const ushort4*)&Shi[(size_t)(rb + row) * H + cb + c4];
        *(ushort4*)&tl[row][c4] = *(const ushort4*)&Slo[(size_t)(rb + row) * H + cb + c4];
    }
    __syncthreads();
    #pragma unroll
    for (int p = 0; p < 4; ++p) {
        const int row = p * 16 + (t >> 4);      // dst row = src col
        const int c4 = (t & 15) * 4;            // dst col = src row
        ushort4 hv, lv;
        hv.x = th[c4 + 0][row]; hv.y = th[c4 + 1][row];
        hv.z = th[c4 + 2][row]; hv.w = th[c4 + 3][row];
        lv.x = tl[c4 + 0][row]; lv.y = tl[c4 + 1][row];
        lv.z = tl[c4 + 2][row]; lv.w = tl[c4 + 3][row];
        *(ushort4*)&Dhi[(size_t)(cb + row) * H + rb + c4] = hv;
        *(ushort4*)&Dlo[(size_t)(cb + row) * H + rb + c4] = lv;
    }
}

// ---------------------------------------------------------------------------
// matvec from hi/lo planes: y = add + (hi+lo) * x
// ---------------------------------------------------------------------------
__global__ void matvec_add2_k(float* __restrict__ y,
                              const unsigned short* __restrict__ Phi,
                              const unsigned short* __restrict__ Plo,
                              const float* __restrict__ x, const float* __restrict__ add)
{
    const int wave = threadIdx.x >> 6;
    const int lane = threadIdx.x & 63;
    const int row = blockIdx.x * 4 + wave;
    const unsigned short* ph = Phi + (size_t)row * H;
    const unsigned short* pl = Plo + (size_t)row * H;
    float s = 0.0f;
    #pragma unroll
    for (int j = 0; j < H / 64; ++j) {
        const float m = bf2f(ph[lane + j * 64]) + bf2f(pl[lane + j * 64]);
        s = fmaf(m, x[lane + j * 64], s);
    }
    #pragma unroll
    for (int off = 32; off; off >>= 1)
        s += __shfl_down(s, off, 64);
    if (lane == 0) y[row] = add[row] + s;
}

// ---------------------------------------------------------------------------
// chain GEMM (1024^3): Q = L * R, all operands/results as bf16 hi/lo planes.
// L given row-major (Lhi/Llo), R given transposed (RThi/RTlo = R^T row-major).
// 4-product split-2 MFMA; epilogue writes Q planes normal AND transposed.
// 64x64 tile, BK=32, 4 waves, double-buffered global_load_lds staging.
// ---------------------------------------------------------------------------
__launch_bounds__(256)
__global__ void chain_gemm_k(const unsigned short* __restrict__ Lhi,
                             const unsigned short* __restrict__ Llo,
                             const unsigned short* __restrict__ RThi,
                             const unsigned short* __restrict__ RTlo,
                             unsigned short* __restrict__ Qhi,
                             unsigned short* __restrict__ Qlo,
                             unsigned short* __restrict__ QhiT,
                             unsigned short* __restrict__ QloT)
{
    __shared__ unsigned short sA[2][2][64][32];
    __shared__ unsigned short sB[2][2][64][32];

    const int tid = threadIdx.x;
    const int wave = tid >> 6, lane = tid & 63;
    const int lg = lane >> 4, lm = lane & 15;
    const int wr2 = (wave >> 1) * 32, wc2 = (wave & 1) * 32;
    // XCD-aware bijective swizzle (grid 256 = 8 XCDs x 32)
    const int bid = blockIdx.y * gridDim.x + blockIdx.x;
    const int swz = (bid & 7) * 32 + (bid >> 3);
    const int m0 = (swz >> 4) * 64, n0 = (swz & 15) * 64;

    const int srow = tid >> 2, skg = tid & 3;
    const int sks = skg ^ (srow & 3);                // source pre-swizzle
    const size_t gA = (size_t)(m0 + srow) * H + sks * 8;
    const size_t gB = (size_t)(n0 + srow) * H + sks * 8;

    f32x4 acc[2][2] = {};

    #define STAGE_CH(k0, b) do {                                     \
        gload16(Lhi  + gA + (k0), &sA[b][0][srow][skg * 8]);         \
        gload16(Llo  + gA + (k0), &sA[b][1][srow][skg * 8]);         \
        gload16(RThi + gB + (k0), &sB[b][0][srow][skg * 8]);         \
        gload16(RTlo + gB + (k0), &sB[b][1][srow][skg * 8]);         \
    } while (0)

    STAGE_CH(0, 0);
    __syncthreads();
    int buf = 0;
    for (int t = 0; t < H / 32; ++t) {
        if (t + 1 < H / 32) STAGE_CH((t + 1) * 32, buf ^ 1);
        bf16x8 ah[2], al[2], bh[2], bl[2];
        #pragma unroll
        for (int i = 0; i < 2; ++i) {
            const int row = wr2 + i * 16 + lm;
            const int sl = lg ^ (row & 3);
            ah[i] = *(const bf16x8*)&sA[buf][0][row][sl * 8];
            al[i] = *(const bf16x8*)&sA[buf][1][row][sl * 8];
            const int rn = wc2 + i * 16 + lm;
            const int sn = lg ^ (rn & 3);
            bh[i] = *(const bf16x8*)&sB[buf][0][rn][sn * 8];
            bl[i] = *(const bf16x8*)&sB[buf][1][rn][sn * 8];
        }
        #pragma unroll
        for (int i = 0; i < 2; ++i)
            #pragma unroll
            for (int j = 0; j < 2; ++j) {
                acc[i][j] = __builtin_amdgcn_mfma_f32_16x16x32_bf16(ah[i], bh[j], acc[i][j], 0, 0, 0);
                acc[i][j] = __builtin_amdgcn_mfma_f32_16x16x32_bf16(ah[i], bl[j], acc[i][j], 0, 0, 0);
                acc[i][j] = __builtin_amdgcn_mfma_f32_16x16x32_bf16(al[i], bh[j], acc[i][j], 0, 0, 0);
                acc[i][j] = __builtin_amdgcn_mfma_f32_16x16x32_bf16(al[i], bl[j], acc[i][j], 0, 0, 0);
            }
        __syncthreads();
        buf ^= 1;
    }
    #undef STAGE_CH

    #pragma unroll
    for (int i = 0; i < 2; ++i) {
        const int row0 = m0 + wr2 + i * 16 + lg * 4;
        #pragma unroll
        for (int j = 0; j < 2; ++j) {
            const int col = n0 + wc2 + j * 16 + lm;
            unsigned short hs[4], ls[4];
            #pragma unroll
            for (int r = 0; r < 4; ++r) {
                split2(acc[i][j][r], hs[r], ls[r]);
                Qhi[(size_t)(row0 + r) * H + col] = hs[r];
                Qlo[(size_t)(row0 + r) * H + col] = ls[r];
            }
            ushort4 th, tl;
            th.x = hs[0]; th.y = hs[1]; th.z = hs[2]; th.w = hs[3];
            tl.x = ls[0]; tl.y = ls[1]; tl.z = ls[2]; tl.w = ls[3];
            *(ushort4*)&QhiT[(size_t)col * H + row0] = th;
            *(ushort4*)&QloT[(size_t)col * H + row0] = tl;
        }
    }
}

// ---------------------------------------------------------------------------
// X [1024][8192] fp32 -> transposed bf16 planes XT [8192][1024] (hi/lo)
// ---------------------------------------------------------------------------
__global__ void transpose_split_X_k(const float* __restrict__ X,
                                    unsigned short* __restrict__ XhiT,
                                    unsigned short* __restrict__ XloT)
{
    __shared__ float ts[64][65];
    const int t = threadIdx.x;
    const int n0 = blockIdx.x * 64;   // batch base
    const int k0 = blockIdx.y * 64;   // k base
    #pragma unroll
    for (int p = 0; p < 4; ++p) {
        const int row = p * 16 + (t >> 4);       // k-local
        const int c4 = (t & 15) * 4;             // n-local
        const float4 v = *(const float4*)&X[(size_t)(k0 + row) * BATCH + n0 + c4];
        ts[row][c4 + 0] = v.x; ts[row][c4 + 1] = v.y;
        ts[row][c4 + 2] = v.z; ts[row][c4 + 3] = v.w;
    }
    __syncthreads();
    #pragma unroll
    for (int p = 0; p < 2; ++p) {
        const int n = p * 32 + (t >> 3);         // n-local
        const int kc = (t & 7) * 8;              // k-local chunk
        bf16x8 hv, lv;
        #pragma unroll
        for (int q = 0; q < 8; ++q) {
            unsigned short hh, ll;
            split2(ts[kc + q][n], hh, ll);
            hv[q] = (short)hh;
            lv[q] = (short)ll;
        }
        *(bf16x8*)&XhiT[(size_t)(n0 + n) * H + k0 + kc] = hv;
        *(bf16x8*)&XloT[(size_t)(n0 + n) * H + k0 + kc] = lv;
    }
}

// ---------------------------------------------------------------------------
// big GEMM (pre-split path): C = P * X + bias, P/XT as bf16 planes.
// 128x128 tile, BK=32, 4 waves (64x64 each), 3 products, dbuf gload_lds.
// ---------------------------------------------------------------------------
__launch_bounds__(256)
__global__ void big_gemm_presplit_k(const unsigned short* __restrict__ Phi,
                                    const unsigned short* __restrict__ Plo,
                                    const unsigned short* __restrict__ XhiT,
                                    const unsigned short* __restrict__ XloT,
                                    float* __restrict__ C, const float* __restrict__ bias)
{
    __shared__ unsigned short sA[2][2][128][32];
    __shared__ unsigned short sB[2][2][128][32];

    const int tid = threadIdx.x;
    const int wave = tid >> 6, lane = tid & 63;
    const int lg = lane >> 4, lm = lane & 15;
    const int wr2 = (wave >> 1) * 64, wc2 = (wave & 1) * 64;
    const int m0 = blockIdx.y * 128, n0 = blockIdx.x * 128;

    f32x4 acc[4][4] = {};

    #define STAGE_BG(k0, b) do {                                                        \
        _Pragma("unroll")                                                               \
        for (int it = 0; it < 2; ++it) {                                                \
            const int idx = tid + it * 256;                                             \
            const int row = idx >> 2, kg = idx & 3;                                     \
            const int ks = kg ^ (row & 3);                                              \
            gload16(Phi  + (size_t)(m0 + row) * H + (k0) + ks * 8, &sA[b][0][row][kg * 8]); \
            gload16(Plo  + (size_t)(m0 + row) * H + (k0) + ks * 8, &sA[b][1][row][kg * 8]); \
            gload16(XhiT + (size_t)(n0 + row) * H + (k0) + ks * 8, &sB[b][0][row][kg * 8]); \
            gload16(XloT + (size_t)(n0 + row) * H + (k0) + ks * 8, &sB[b][1][row][kg * 8]); \
        }                                                                               \
    } while (0)

    STAGE_BG(0, 0);
    __syncthreads();
    int buf = 0;
    for (int t = 0; t < H / 32; ++t) {
        if (t + 1 < H / 32) STAGE_BG((t + 1) * 32, buf ^ 1);
        bf16x8 ah[4], al[4], bh[4], bl[4];
        #pragma unroll
        for (int i = 0; i < 4; ++i) {
            const int row = wr2 + i * 16 + lm;
            const int sl = lg ^ (row & 3);
            ah[i] = *(const bf16x8*)&sA[buf][0][row][sl * 8];
            al[i] = *(const bf16x8*)&sA[buf][1][row][sl * 8];
            const int rn = wc2 + i * 16 + lm;
            const int sn = lg ^ (rn & 3);
            bh[i] = *(const bf16x8*)&sB[buf][0][rn][sn * 8];
            bl[i] = *(const bf16x8*)&sB[buf][1][rn][sn * 8];
        }
        #pragma unroll
        for (int i = 0; i < 4; ++i)
            #pragma unroll
            for (int j = 0; j < 4; ++j) {
                acc[i][j] = __builtin_amdgcn_mfma_f32_16x16x32_bf16(ah[i], bh[j], acc[i][j], 0, 0, 0);
                acc[i][j] = __builtin_amdgcn_mfma_f32_16x16x32_bf16(ah[i], bl[j], acc[i][j], 0, 0, 0);
                acc[i][j] = __builtin_amdgcn_mfma_f32_16x16x32_bf16(al[i], bh[j], acc[i][j], 0, 0, 0);
            }
        __syncthreads();
        buf ^= 1;
    }
    #undef STAGE_BG

    #pragma unroll
    for (int i = 0; i < 4; ++i) {
        const int row0 = m0 + wr2 + i * 16 + lg * 4;
        #pragma unroll
        for (int r = 0; r < 4; ++r) {
            const float bv = bias[row0 + r];
            float* dst = &C[(size_t)(row0 + r) * BATCH + n0 + wc2 + lm];
            #pragma unroll
            for (int j = 0; j < 4; ++j)
                dst[j * 16] = acc[i][j][r] + bv;
        }
    }
}

// ---------------------------------------------------------------------------
// big GEMM fallback (X split in-kernel) — round-2 kernel, known-good 68us
// ---------------------------------------------------------------------------
#define PADK 40

__launch_bounds__(256)
__global__ void big_gemm_fallback_k(const unsigned short* __restrict__ Ahi_g,
                                    const unsigned short* __restrict__ Alo_g,
                                    const float* __restrict__ X, float* __restrict__ C,
                                    const float* __restrict__ bias)
{
    __shared__ unsigned short Ahi[128][PADK], Alo[128][PADK];
    __shared__ unsigned short Bhi[128][PADK], Blo[128][PADK];

    const int tid = threadIdx.x;
    const int wave = tid >> 6;
    const int lane = tid & 63;
    const int wr = (wave >> 1) * 64;
    const int wc = (wave & 1) * 64;
    const int m0 = blockIdx.y * 128;
    const int n0 = blockIdx.x * 128;
    const int lg = lane >> 4;
    const int lm = lane & 15;

    f32x4 acc[4][4] = {};

    for (int k0 = 0; k0 < H; k0 += 32) {
        #pragma unroll
        for (int a2 = 0; a2 < 2; ++a2) {
            const int id = tid + a2 * 256;
            const int row = id >> 2;
            const int ko = id & 3;
            const size_t g = (size_t)(m0 + row) * H + k0 + ko * 8;
            *(bf16x8*)&Ahi[row][ko * 8] = *(const bf16x8*)&Ahi_g[g];
            *(bf16x8*)&Alo[row][ko * 8] = *(const bf16x8*)&Alo_g[g];
        }
        #pragma unroll
        for (int a2 = 0; a2 < 2; ++a2) {
            const int id = tid + a2 * 256;
            const int n = id & 127;
            const int ko = id >> 7;
            const float* src = &X[(size_t)(k0 + ko * 8) * BATCH + n0 + n];
            bf16x8 bh, bl;
            #pragma unroll
            for (int i = 0; i < 8; ++i) {
                unsigned short hh, ll;
                split2(src[(size_t)i * BATCH], hh, ll);
                bh[i] = (short)hh;
                bl[i] = (short)ll;
            }
            *(bf16x8*)&Bhi[n][ko * 8] = bh;
            *(bf16x8*)&Blo[n][ko * 8] = bl;
        }
        __syncthreads();

        bf16x8 ah[4], al[4], bh[4], bl[4];
        #pragma unroll
        for (int i = 0; i < 4; ++i) {
            const int m = wr + i * 16 + lm;
            ah[i] = *(const bf16x8*)&Ahi[m][lg * 8];
            al[i] = *(const bf16x8*)&Alo[m][lg * 8];
            const int n = wc + i * 16 + lm;
            bh[i] = *(const bf16x8*)&Bhi[n][lg * 8];
            bl[i] = *(const bf16x8*)&Blo[n][lg * 8];
        }
        #pragma unroll
        for (int i = 0; i < 4; ++i)
            #pragma unroll
            for (int j = 0; j < 4; ++j) {
                acc[i][j] = __builtin_amdgcn_mfma_f32_16x16x32_bf16(ah[i], bh[j], acc[i][j], 0, 0, 0);
                acc[i][j] = __builtin_amdgcn_mfma_f32_16x16x32_bf16(ah[i], bl[j], acc[i][j], 0, 0, 0);
                acc[i][j] = __builtin_amdgcn_mfma_f32_16x16x32_bf16(al[i], bh[j], acc[i][j], 0, 0, 0);
            }
        __syncthreads();
    }

    #pragma unroll
    for (int i = 0; i < 4; ++i) {
        const int rowb = m0 + wr + i * 16 + lg * 4;
        #pragma unroll
        for (int r = 0; r < 4; ++r) {
            const float bv = bias[rowb + r];
            float* dst = &C[(size_t)(rowb + r) * BATCH + n0 + wc + lm];
            #pragma unroll
            for (int j = 0; j < 4; ++j)
                dst[j * 16] = acc[i][j][r] + bv;
        }
    }
}

// ---------------------------------------------------------------------------
// host-side launcher
// ---------------------------------------------------------------------------
extern "C" void kernel_launch(void* const* d_in, const int* in_sizes, int n_in,
                              void* d_out, int out_size, void* d_ws, size_t ws_size,
                              hipStream_t stream)
{
    const float* x0 = (const float*)d_in[0];
    const float* t0 = (const float*)d_in[1];
    const float* t1 = (const float*)d_in[2];
    const float* W  = (const float*)d_in[3];
    const float* bb = (const float*)d_in[4];
    float* out = (float*)d_out;

    // ws layout: A planes {hi,lo,hiT,loT} (8MB) | cv,v0,v1 | [16MB: XT planes 32MB]
    unsigned short* Ahi  = (unsigned short*)d_ws;
    unsigned short* Alo  = Ahi + HH;
    unsigned short* AhiT = Alo + HH;
    unsigned short* AloT = AhiT + HH;
    float* cv = (float*)(AloT + HH);
    float* v0 = cv + H;
    float* v1 = v0 + H;

    const size_t xtoff = (size_t)16 * 1024 * 1024;
    const bool useXT = ws_size >= xtoff + (size_t)2 * BATCH * H * sizeof(unsigned short);
    unsigned short* XhiT = (unsigned short*)((char*)d_ws + xtoff);
    unsigned short* XloT = XhiT + (size_t)BATCH * H;

    // d_out scratch: two ping-pong plane-sets {hi,lo,hiT,loT}, 8MB each
    unsigned short* PA = (unsigned short*)d_out;
    unsigned short* PB = PA + (size_t)4 * HH;

    build_k<<<HH / 1024, 256, 0, stream>>>(Ahi, Alo, W, t0, t1);
    build_c_k<<<H / 256, 256, 0, stream>>>(cv, v0, bb, t0, t1);
    transpose_pair_k<<<dim3(16, 16), 256, 0, stream>>>(Ahi, Alo, AhiT, AloT);

    // addition chain 1 -> 2 -> 3 -> 6 -> 12 -> 24 -> 25 -> 50
    // SQ : v_2n = v_n + P v_n ; P' = P*P
    // MUL: v_n+1 = c + A v_n  ; P' = A*P
    const int seq[7] = {0, 1, 0, 0, 0, 1, 0};   // 0=SQ, 1=MUL
    unsigned short* cur = Ahi;                  // P_1 = A (planes are consecutive)
    float* vin = v0;
    float* vout = v1;
    for (int s = 0; s < 7; ++s) {
        unsigned short* nxt = (s & 1) ? PB : PA;
        if (seq[s]) {
            matvec_add2_k<<<H / 4, 256, 0, stream>>>(vout, Ahi, Alo, vin, cv);
            chain_gemm_k<<<dim3(16, 16), 256, 0, stream>>>(
                Ahi, Alo, cur + 2 * HH, cur + 3 * HH,
                nxt, nxt + HH, nxt + 2 * HH, nxt + 3 * HH);
        } else {
            matvec_add2_k<<<H / 4, 256, 0, stream>>>(vout, cur, cur + HH, vin, vin);
            chain_gemm_k<<<dim3(16, 16), 256, 0, stream>>>(
                cur, cur + HH, cur + 2 * HH, cur + 3 * HH,
                nxt, nxt + HH, nxt + 2 * HH, nxt + 3 * HH);
        }
        cur = nxt;
        float* tv = vin; vin = vout; vout = tv;
    }
    // cur = P_50 planes (in d_out, s=6 -> PA); vin = v_50

    // copy P50 hi/lo to ws (A^T planes are dead) before C overwrites d_out
    hipMemcpyAsync(AhiT, cur, (size_t)HH * sizeof(unsigned short),
                   hipMemcpyDeviceToDevice, stream);
    hipMemcpyAsync(AloT, cur + HH, (size_t)HH * sizeof(unsigned short),
                   hipMemcpyDeviceToDevice, stream);

    if (useXT) {
        transpose_split_X_k<<<dim3(BATCH / 64, H / 64), 256, 0, stream>>>(x0, XhiT, XloT);
        big_gemm_presplit_k<<<dim3(BATCH / 128, H / 128), 256, 0, stream>>>(
            AhiT, AloT, XhiT, XloT, out, vin);
    } else {
        big_gemm_fallback_k<<<dim3(BATCH / 128, H / 128), 256, 0, stream>>>(
            AhiT, AloT, x0, out, vin);
    }
}

// Round 4
// 189.829 us; speedup vs baseline: 3.2627x; 1.4786x over previous
//
#include <hip/hip_runtime.h>

#define H 1024
#define HH (H * H)
#define BATCH 8192
#define NSTEPS 50

typedef __attribute__((ext_vector_type(8))) short bf16x8;
typedef __attribute__((ext_vector_type(4))) float f32x4;

// ---------------------------------------------------------------------------
// helpers
// ---------------------------------------------------------------------------
__device__ __forceinline__ void split2(float a, unsigned short& h, unsigned short& l)
{
    unsigned u = __float_as_uint(a);
    float r = a - __uint_as_float(u & 0xFFFF0000u);   // exact residual
    h = (unsigned short)(u >> 16);                    // truncated bf16
    l = (unsigned short)((__float_as_uint(r) + 0x8000u) >> 16); // rounded residual
}
__device__ __forceinline__ float bf2f(unsigned short s)
{
    return __uint_as_float(((unsigned)s) << 16);
}
__device__ __forceinline__ void gload16(const void* g, void* l)
{
    __builtin_amdgcn_global_load_lds(
        (const __attribute__((address_space(1))) void*)g,
        (__attribute__((address_space(3))) void*)l, 16, 0, 0);
}

// ---------------------------------------------------------------------------
// build A = I + h*W as bf16 hi/lo planes; c = h*b (fp32, also v0)
// ---------------------------------------------------------------------------
__global__ void build_k(unsigned short* __restrict__ Ahi, unsigned short* __restrict__ Alo,
                        const float* __restrict__ W,
                        const float* __restrict__ t0, const float* __restrict__ t1)
{
    const float h = (t1[0] - t0[0]) / (float)NSTEPS;
    const int i4 = blockIdx.x * 256 + threadIdx.x;   // float4 index
    const int idx = i4 * 4;
    const int r = idx >> 10;
    const int cb = idx & 1023;
    const float4 w = ((const float4*)W)[i4];
    float a[4] = {h * w.x, h * w.y, h * w.z, h * w.w};
    #pragma unroll
    for (int j = 0; j < 4; ++j)
        if (cb + j == r) a[j] += 1.0f;
    ushort4 hv, lv;
    split2(a[0], hv.x, lv.x);
    split2(a[1], hv.y, lv.y);
    split2(a[2], hv.z, lv.z);
    split2(a[3], hv.w, lv.w);
    ((ushort4*)Ahi)[i4] = hv;
    ((ushort4*)Alo)[i4] = lv;
}

__global__ void build_c_k(float* __restrict__ cvec, float* __restrict__ v0,
                          const float* __restrict__ b,
                          const float* __restrict__ t0, const float* __restrict__ t1)
{
    const float h = (t1[0] - t0[0]) / (float)NSTEPS;
    const int i = blockIdx.x * 256 + threadIdx.x;
    const float v = h * b[i];
    cvec[i] = v;
    v0[i] = v;
}

// ---------------------------------------------------------------------------
// transpose a pair of bf16 planes (1024x1024): D = S^T
// ---------------------------------------------------------------------------
__global__ void transpose_pair_k(const unsigned short* __restrict__ Shi,
                                 const unsigned short* __restrict__ Slo,
                                 unsigned short* __restrict__ Dhi,
                                 unsigned short* __restrict__ Dlo)
{
    __shared__ unsigned short th[64][68], tl[64][68];
    const int t = threadIdx.x;
    const int cb = blockIdx.x * 64;  // src col base
    const int rb = blockIdx.y * 64;  // src row base
    #pragma unroll
    for (int p = 0; p < 4; ++p) {
        const int row = p * 16 + (t >> 4);
        const int c4 = (t & 15) * 4;
        *(ushort4*)&th[row][c4] = *(const ushort4*)&Shi[(size_t)(rb + row) * H + cb + c4];
        *(ushort4*)&tl[row][c4] = *(const ushort4*)&Slo[(size_t)(rb + row) * H + cb + c4];
    }
    __syncthreads();
    #pragma unroll
    for (int p = 0; p < 4; ++p) {
        const int row = p * 16 + (t >> 4);      // dst row = src col
        const int c4 = (t & 15) * 4;            // dst col = src row
        ushort4 hv, lv;
        hv.x = th[c4 + 0][row]; hv.y = th[c4 + 1][row];
        hv.z = th[c4 + 2][row]; hv.w = th[c4 + 3][row];
        lv.x = tl[c4 + 0][row]; lv.y = tl[c4 + 1][row];
        lv.z = tl[c4 + 2][row]; lv.w = tl[c4 + 3][row];
        *(ushort4*)&Dhi[(size_t)(cb + row) * H + rb + c4] = hv;
        *(ushort4*)&Dlo[(size_t)(cb + row) * H + rb + c4] = lv;
    }
}

// ---------------------------------------------------------------------------
// fused chain step: 272 blocks x 512 threads.
//  blocks [0,256):  Q = L * R  (GEMM, 64x64 tile, 8 waves, in-block split-K=2,
//                   3-product split-2 bf16 MFMA, dbuf gload_lds staging)
//  blocks [256,272): vout = addv + (Lhi+Llo) * vin   (matvec, 64 rows/block)
// L row-major planes; RT = R^T row-major planes. Q written as hi/lo planes,
// normal layout always, transposed layout iff WRITE_T.
// ---------------------------------------------------------------------------
template<bool WRITE_T>
__launch_bounds__(512)
__global__ void chain_fused_k(const unsigned short* __restrict__ Lhi,
                              const unsigned short* __restrict__ Llo,
                              const unsigned short* __restrict__ RThi,
                              const unsigned short* __restrict__ RTlo,
                              unsigned short* __restrict__ Qhi,
                              unsigned short* __restrict__ Qlo,
                              unsigned short* __restrict__ QhiT,
                              unsigned short* __restrict__ QloT,
                              const float* __restrict__ vin,
                              const float* __restrict__ addv,
                              float* __restrict__ vout)
{
    __shared__ unsigned short sA[2][2][2][64][32];  // [dbuf][khalf][plane][row][k] 32KB
    __shared__ unsigned short sB[2][2][2][64][32];  // 32KB

    const int tid = threadIdx.x;
    const int bid = blockIdx.x;
    const int wave = tid >> 6, lane = tid & 63;

    if (bid >= 256) {
        // ---- matvec blocks ----
        const int rowbase = (bid - 256) * 64 + wave * 8;
        const float4* xq = (const float4*)vin + lane * 4;   // k in [lane*16, lane*16+16)
        float4 xv[4];
        #pragma unroll
        for (int q = 0; q < 4; ++q) xv[q] = xq[q];
        #pragma unroll
        for (int rr = 0; rr < 8; ++rr) {
            const int row = rowbase + rr;
            const unsigned short* mh = Lhi + (size_t)row * H + lane * 16;
            const unsigned short* ml = Llo + (size_t)row * H + lane * 16;
            bf16x8 h0 = *(const bf16x8*)&mh[0];
            bf16x8 h1 = *(const bf16x8*)&mh[8];
            bf16x8 l0 = *(const bf16x8*)&ml[0];
            bf16x8 l1 = *(const bf16x8*)&ml[8];
            float s = 0.0f;
            #pragma unroll
            for (int q = 0; q < 8; ++q) {
                const float m0v = bf2f((unsigned short)h0[q]) + bf2f((unsigned short)l0[q]);
                const float m1v = bf2f((unsigned short)h1[q]) + bf2f((unsigned short)l1[q]);
                const float* xf = (const float*)xv;
                s = fmaf(m0v, xf[q], s);
                s = fmaf(m1v, xf[8 + q], s);
            }
            #pragma unroll
            for (int off = 32; off; off >>= 1)
                s += __shfl_down(s, off, 64);
            if (lane == 0) vout[row] = addv[row] + s;
        }
        return;
    }

    // ---- GEMM blocks ----
    const int lg = lane >> 4, lm = lane & 15;
    const int half = wave >> 2;               // k-half owner
    const int wq = wave & 3;
    const int wr2 = (wq >> 1) * 32, wc2 = (wq & 1) * 32;
    // XCD-aware bijective swizzle over the 256 GEMM blocks
    const int swz = (bid & 7) * 32 + (bid >> 3);
    const int m0 = (swz >> 4) * 64, n0 = (swz & 15) * 64;

    f32x4 acc[2][2] = {};

    #define STAGE(tt, b) do {                                                      \
        _Pragma("unroll")                                                          \
        for (int it = 0; it < 4; ++it) {                                           \
            const int c = tid + it * 512;                                          \
            const int mat   = c >> 10;                                             \
            const int khalf = (c >> 9) & 1;                                        \
            const int plane = (c >> 8) & 1;                                        \
            const int row   = (c >> 2) & 63;                                       \
            const int kc    = c & 3;                                               \
            const int ks    = kc ^ ((row >> 1) & 3);                               \
            const size_t gofs = (size_t)khalf * 512 + (size_t)(tt) * 32 + ks * 8;  \
            const unsigned short* g = mat ? (plane ? RTlo : RThi)                  \
                                          : (plane ? Llo : Lhi);                   \
            const int rbase = mat ? n0 : m0;                                       \
            unsigned short* dst = mat ? &sB[b][khalf][plane][row][kc * 8]          \
                                      : &sA[b][khalf][plane][row][kc * 8];         \
            gload16(g + (size_t)(rbase + row) * H + gofs, dst);                    \
        }                                                                          \
    } while (0)

    STAGE(0, 0);
    __syncthreads();
    int buf = 0;
    for (int t = 0; t < 16; ++t) {
        if (t + 1 < 16) STAGE(t + 1, buf ^ 1);
        bf16x8 ah[2], al[2], bh[2], bl[2];
        #pragma unroll
        for (int i = 0; i < 2; ++i) {
            const int row = wr2 + i * 16 + lm;
            const int sl = lg ^ ((row >> 1) & 3);
            ah[i] = *(const bf16x8*)&sA[buf][half][0][row][sl * 8];
            al[i] = *(const bf16x8*)&sA[buf][half][1][row][sl * 8];
            const int rn = wc2 + i * 16 + lm;
            const int sn = lg ^ ((rn >> 1) & 3);
            bh[i] = *(const bf16x8*)&sB[buf][half][0][rn][sn * 8];
            bl[i] = *(const bf16x8*)&sB[buf][half][1][rn][sn * 8];
        }
        #pragma unroll
        for (int i = 0; i < 2; ++i)
            #pragma unroll
            for (int j = 0; j < 2; ++j) {
                acc[i][j] = __builtin_amdgcn_mfma_f32_16x16x32_bf16(ah[i], bh[j], acc[i][j], 0, 0, 0);
                acc[i][j] = __builtin_amdgcn_mfma_f32_16x16x32_bf16(ah[i], bl[j], acc[i][j], 0, 0, 0);
                acc[i][j] = __builtin_amdgcn_mfma_f32_16x16x32_bf16(al[i], bh[j], acc[i][j], 0, 0, 0);
            }
        __syncthreads();
        buf ^= 1;
    }
    #undef STAGE

    // cross-half reduce via LDS (padded stride 17 floats to avoid conflicts)
    float* red = (float*)&sA[0][0][0][0][0];
    const int ridx = wq * 64 + lane;
    if (half == 1) {
        float* dst = red + (size_t)ridx * 17;
        #pragma unroll
        for (int i = 0; i < 2; ++i)
            #pragma unroll
            for (int j = 0; j < 2; ++j)
                *(f32x4*)&dst[(i * 2 + j) * 4] = acc[i][j];
    }
    __syncthreads();
    if (half == 0) {
        const float* src = red + (size_t)ridx * 17;
        #pragma unroll
        for (int i = 0; i < 2; ++i)
            #pragma unroll
            for (int j = 0; j < 2; ++j) {
                const f32x4 p = *(const f32x4*)&src[(i * 2 + j) * 4];
                acc[i][j] += p;
            }

        // epilogue: row = m0+wr2+i*16+lg*4+r, col = n0+wc2+j*16+lm (m89 layout)
        #pragma unroll
        for (int i = 0; i < 2; ++i) {
            const int row0 = m0 + wr2 + i * 16 + lg * 4;
            #pragma unroll
            for (int j = 0; j < 2; ++j) {
                const int col = n0 + wc2 + j * 16 + lm;
                unsigned short hs[4], ls[4];
                #pragma unroll
                for (int r = 0; r < 4; ++r) {
                    split2(acc[i][j][r], hs[r], ls[r]);
                    Qhi[(size_t)(row0 + r) * H + col] = hs[r];
                    Qlo[(size_t)(row0 + r) * H + col] = ls[r];
                }
                if (WRITE_T) {
                    ushort4 th, tl;
                    th.x = hs[0]; th.y = hs[1]; th.z = hs[2]; th.w = hs[3];
                    tl.x = ls[0]; tl.y = ls[1]; tl.z = ls[2]; tl.w = ls[3];
                    *(ushort4*)&QhiT[(size_t)col * H + row0] = th;
                    *(ushort4*)&QloT[(size_t)col * H + row0] = tl;
                }
            }
        }
    }
}

// ---------------------------------------------------------------------------
// big GEMM: C = P * X + bias. P as bf16 hi/lo planes (row-major), X fp32
// split in-kernel. 128x128 tile, BK=32, 4 waves, 3 products.
// ---------------------------------------------------------------------------
#define PADK 40

__launch_bounds__(256)
__global__ void big_gemm_k(const unsigned short* __restrict__ Ahi_g,
                           const unsigned short* __restrict__ Alo_g,
                           const float* __restrict__ X, float* __restrict__ C,
                           const float* __restrict__ bias)
{
    __shared__ unsigned short Ahi[128][PADK], Alo[128][PADK];
    __shared__ unsigned short Bhi[128][PADK], Blo[128][PADK];

    const int tid = threadIdx.x;
    const int wave = tid >> 6;
    const int lane = tid & 63;
    const int wr = (wave >> 1) * 64;
    const int wc = (wave & 1) * 64;
    const int m0 = blockIdx.y * 128;
    const int n0 = blockIdx.x * 128;
    const int lg = lane >> 4;
    const int lm = lane & 15;

    f32x4 acc[4][4] = {};

    for (int k0 = 0; k0 < H; k0 += 32) {
        #pragma unroll
        for (int a2 = 0; a2 < 2; ++a2) {
            const int id = tid + a2 * 256;
            const int row = id >> 2;
            const int ko = id & 3;
            const size_t g = (size_t)(m0 + row) * H + k0 + ko * 8;
            *(bf16x8*)&Ahi[row][ko * 8] = *(const bf16x8*)&Ahi_g[g];
            *(bf16x8*)&Alo[row][ko * 8] = *(const bf16x8*)&Alo_g[g];
        }
        #pragma unroll
        for (int a2 = 0; a2 < 2; ++a2) {
            const int id = tid + a2 * 256;
            const int n = id & 127;
            const int ko = id >> 7;
            const float* src = &X[(size_t)(k0 + ko * 8) * BATCH + n0 + n];
            bf16x8 bh, bl;
            #pragma unroll
            for (int i = 0; i < 8; ++i) {
                unsigned short hh, ll;
                split2(src[(size_t)i * BATCH], hh, ll);
                bh[i] = (short)hh;
                bl[i] = (short)ll;
            }
            *(bf16x8*)&Bhi[n][ko * 8] = bh;
            *(bf16x8*)&Blo[n][ko * 8] = bl;
        }
        __syncthreads();

        bf16x8 ah[4], al[4], bh[4], bl[4];
        #pragma unroll
        for (int i = 0; i < 4; ++i) {
            const int m = wr + i * 16 + lm;
            ah[i] = *(const bf16x8*)&Ahi[m][lg * 8];
            al[i] = *(const bf16x8*)&Alo[m][lg * 8];
            const int n = wc + i * 16 + lm;
            bh[i] = *(const bf16x8*)&Bhi[n][lg * 8];
            bl[i] = *(const bf16x8*)&Blo[n][lg * 8];
        }
        #pragma unroll
        for (int i = 0; i < 4; ++i)
            #pragma unroll
            for (int j = 0; j < 4; ++j) {
                acc[i][j] = __builtin_amdgcn_mfma_f32_16x16x32_bf16(ah[i], bh[j], acc[i][j], 0, 0, 0);
                acc[i][j] = __builtin_amdgcn_mfma_f32_16x16x32_bf16(ah[i], bl[j], acc[i][j], 0, 0, 0);
                acc[i][j] = __builtin_amdgcn_mfma_f32_16x16x32_bf16(al[i], bh[j], acc[i][j], 0, 0, 0);
            }
        __syncthreads();
    }

    #pragma unroll
    for (int i = 0; i < 4; ++i) {
        const int rowb = m0 + wr + i * 16 + lg * 4;
        #pragma unroll
        for (int r = 0; r < 4; ++r) {
            const float bv = bias[rowb + r];
            float* dst = &C[(size_t)(rowb + r) * BATCH + n0 + wc + lm];
            #pragma unroll
            for (int j = 0; j < 4; ++j)
                dst[j * 16] = acc[i][j][r] + bv;
        }
    }
}

// ---------------------------------------------------------------------------
// host-side launcher
// ---------------------------------------------------------------------------
extern "C" void kernel_launch(void* const* d_in, const int* in_sizes, int n_in,
                              void* d_out, int out_size, void* d_ws, size_t ws_size,
                              hipStream_t stream)
{
    const float* x0 = (const float*)d_in[0];
    const float* t0 = (const float*)d_in[1];
    const float* t1 = (const float*)d_in[2];
    const float* W  = (const float*)d_in[3];
    const float* bb = (const float*)d_in[4];
    float* out = (float*)d_out;

    // ws layout: A planes {hi,lo,hiT,loT} (8MB) | cv,v0,v1
    unsigned short* Ahi  = (unsigned short*)d_ws;
    unsigned short* Alo  = Ahi + HH;
    unsigned short* AhiT = Alo + HH;
    unsigned short* AloT = AhiT + HH;
    float* cv = (float*)(AloT + HH);
    float* v0 = cv + H;
    float* v1 = v0 + H;

    // d_out scratch: two ping-pong plane-sets {hi,lo,hiT,loT}, 8MB each (16MB),
    // fully overwritten by the final 32MB C write.
    unsigned short* PA = (unsigned short*)d_out;
    unsigned short* PB = PA + (size_t)4 * HH;

    build_k<<<HH / 1024, 256, 0, stream>>>(Ahi, Alo, W, t0, t1);
    build_c_k<<<H / 256, 256, 0, stream>>>(cv, v0, bb, t0, t1);
    transpose_pair_k<<<dim3(16, 16), 256, 0, stream>>>(Ahi, Alo, AhiT, AloT);

    // addition chain 1 -> 2 -> 3 -> 6 -> 12 -> 24 -> 25 -> 50
    // SQ : v_2n = v_n + P v_n ; P' = P*P   (L = P, addv = vin)
    // MUL: v_n+1 = c + A v_n  ; P' = A*P   (L = A, addv = cv)
    const int seq[7] = {0, 1, 0, 0, 0, 1, 0};   // 0=SQ, 1=MUL
    unsigned short* cur = Ahi;                  // P_1 = A (4 consecutive planes)
    float* vin = v0;
    float* vout = v1;
    for (int s = 0; s < 7; ++s) {
        const unsigned short* L  = seq[s] ? Ahi : cur;
        const unsigned short* Ll = seq[s] ? Alo : cur + HH;
        const float* addv = seq[s] ? cv : vin;
        if (s < 6) {
            unsigned short* nxt = (s & 1) ? PB : PA;
            chain_fused_k<true><<<272, 512, 0, stream>>>(
                L, Ll, cur + 2 * HH, cur + 3 * HH,
                nxt, nxt + HH, nxt + 2 * HH, nxt + 3 * HH,
                vin, addv, vout);
            cur = nxt;
        } else {
            // final step: write P_50 normal planes straight into ws (A planes
            // are dead), skip transposed output (never consumed).
            chain_fused_k<false><<<272, 512, 0, stream>>>(
                L, Ll, cur + 2 * HH, cur + 3 * HH,
                Ahi, Alo, nullptr, nullptr,
                vin, addv, vout);
            cur = Ahi;
        }
        float* tv = vin; vin = vout; vout = tv;
    }
    // cur = P_50 planes (in ws); vin = v_50

    // out = P_50 * x0 + v_50 (matrix cores, 3-product split-2)
    big_gemm_k<<<dim3(BATCH / 128, H / 128), 256, 0, stream>>>(
        Ahi, Alo, x0, out, vin);
}